// Round 1
// baseline (1014.090 us; speedup 1.0000x reference)
//
#include <hip/hip_runtime.h>

#define TDIM 32768
#define KDIM 2048
#define NDIM 768
#define EDIM 64
#define RDIM 16
#define SCALE 2.0f

#define BM 128
#define BN 128
#define BK 32
#define PK 40      // padded LDS row length (elems): 80B stride -> uniform bank spread
#define MAXMT 320  // worst-case sum of ceil(m_e/BM) = T/BM + E = 256 + 64

typedef __bf16 bf16;
typedef __attribute__((ext_vector_type(8))) __bf16 bf16x8;
typedef __attribute__((ext_vector_type(4))) __bf16 bf16x4;
typedef __attribute__((ext_vector_type(4))) float f32x4;

__global__ __launch_bounds__(256, 2)
void lora_moe_kernel(const float* __restrict__ x,
                     const int* __restrict__ m_sizes,
                     const float* __restrict__ w_base,
                     const float* __restrict__ w_a,
                     const float* __restrict__ w_b,
                     float* __restrict__ out)
{
    __shared__ bf16 As[BM][PK];        // x tile,   [m][k]
    __shared__ bf16 Bs[BN][PK];        // w tile,   [n][k] (transposed on stage)
    __shared__ bf16 WaS[RDIM][PK];     // w_a tile, [r][k] (transposed on stage)

    const int tid  = threadIdx.x;
    const int lane = tid & 63;
    const int wave = tid >> 6;
    const int wm   = wave >> 1;        // 0..1 : which 64-row half
    const int wn   = wave & 1;         // 0..1 : which 64-col half
    const int quad = lane >> 4;        // 0..3
    const int lrow = lane & 15;

    // ---- map blockIdx.y -> (expert e, tile row start, valid rows) ----
    int tile = blockIdx.y;
    int e = -1, tstart = 0, rows = 0;
    {
        int row0 = 0, acc = 0;
        for (int i = 0; i < EDIM; ++i) {
            int m = m_sizes[i];
            int nt = (m + BM - 1) >> 7;
            if (tile < acc + nt) {
                e = i;
                int lt = tile - acc;
                tstart = row0 + (lt << 7);
                rows = m - (lt << 7);
                if (rows > BM) rows = BM;
                break;
            }
            acc += nt;
            row0 += m;
        }
    }
    if (e < 0) return;

    const int n0 = blockIdx.x * BN;

    const float* wb_e  = w_base + (size_t)e * KDIM * NDIM;
    const float* wa_e  = w_a    + (size_t)e * KDIM * RDIM;
    const float* wbb_e = w_b    + (size_t)e * RDIM * NDIM;

    f32x4 acc[4][4];   // base accum: 64x64 per wave, 16 subtiles
    f32x4 accA[4];     // lora-A accum: 64x16 per wave (duplicated across wn)
    #pragma unroll
    for (int i = 0; i < 4; ++i) {
        accA[i] = (f32x4){0.f, 0.f, 0.f, 0.f};
        #pragma unroll
        for (int j = 0; j < 4; ++j) acc[i][j] = (f32x4){0.f, 0.f, 0.f, 0.f};
    }

    // staging thread mappings
    const int arow  = tid >> 1;             // 0..127
    const int akh   = (tid & 1) * 16;       // 0 or 16
    const int agrow = tstart + (arow < rows ? arow : rows - 1);  // clamp OOB rows
    const float* aptr = x + (size_t)agrow * KDIM + akh;

    const int bn  = tid & 127;              // 0..127 (n within tile)
    const int bg0 = (tid >> 7) * 4;         // 0 or 4 (k-group base; group = 4 k)

    const int war = tid & 15;               // r
    const int wag = tid >> 4;               // k-group; only wag < 8 active

    for (int kk = 0; kk < KDIM; kk += BK) {
        __syncthreads();
        // ---- stage A (x): 128x32 fp32 -> bf16, k-contiguous ----
        {
            const float* p = aptr + kk;
            float4 f0 = *reinterpret_cast<const float4*>(p);
            float4 f1 = *reinterpret_cast<const float4*>(p + 4);
            float4 f2 = *reinterpret_cast<const float4*>(p + 8);
            float4 f3 = *reinterpret_cast<const float4*>(p + 12);
            bf16x8 v0, v1;
            v0[0]=(bf16)f0.x; v0[1]=(bf16)f0.y; v0[2]=(bf16)f0.z; v0[3]=(bf16)f0.w;
            v0[4]=(bf16)f1.x; v0[5]=(bf16)f1.y; v0[6]=(bf16)f1.z; v0[7]=(bf16)f1.w;
            v1[0]=(bf16)f2.x; v1[1]=(bf16)f2.y; v1[2]=(bf16)f2.z; v1[3]=(bf16)f2.w;
            v1[4]=(bf16)f3.x; v1[5]=(bf16)f3.y; v1[6]=(bf16)f3.z; v1[7]=(bf16)f3.w;
            *reinterpret_cast<bf16x8*>(&As[arow][akh])     = v0;
            *reinterpret_cast<bf16x8*>(&As[arow][akh + 8]) = v1;
        }
        // ---- stage B (w_base): [k][n] -> Bs[n][k] (transpose via strided loads) ----
        {
            #pragma unroll
            for (int gi = 0; gi < 4; ++gi) {
                int k = (bg0 + gi) * 4;
                const float* p = wb_e + (size_t)(kk + k) * NDIM + n0 + bn;
                float a0 = p[0];
                float a1 = p[NDIM];
                float a2 = p[2 * NDIM];
                float a3 = p[3 * NDIM];
                bf16x4 v; v[0]=(bf16)a0; v[1]=(bf16)a1; v[2]=(bf16)a2; v[3]=(bf16)a3;
                *reinterpret_cast<bf16x4*>(&Bs[bn][k]) = v;
            }
        }
        // ---- stage w_a: [k][r] -> WaS[r][k] ----
        if (wag < 8) {
            int k = wag * 4;
            const float* p = wa_e + (size_t)(kk + k) * RDIM + war;
            bf16x4 v;
            v[0]=(bf16)p[0]; v[1]=(bf16)p[RDIM]; v[2]=(bf16)p[2*RDIM]; v[3]=(bf16)p[3*RDIM];
            *reinterpret_cast<bf16x4*>(&WaS[war][k]) = v;
        }
        __syncthreads();
        // ---- compute ----
        bf16x8 af[4];
        #pragma unroll
        for (int i = 0; i < 4; ++i)
            af[i] = *reinterpret_cast<const bf16x8*>(&As[wm*64 + i*16 + lrow][quad*8]);
        bf16x8 wf = *reinterpret_cast<const bf16x8*>(&WaS[lrow][quad*8]);
        #pragma unroll
        for (int j = 0; j < 4; ++j) {
            bf16x8 bfr = *reinterpret_cast<const bf16x8*>(&Bs[wn*64 + j*16 + lrow][quad*8]);
            #pragma unroll
            for (int i = 0; i < 4; ++i)
                acc[i][j] = __builtin_amdgcn_mfma_f32_16x16x32_bf16(af[i], bfr, acc[i][j], 0, 0, 0);
        }
        #pragma unroll
        for (int i = 0; i < 4; ++i)
            accA[i] = __builtin_amdgcn_mfma_f32_16x16x32_bf16(af[i], wf, accA[i], 0, 0, 0);
    }

    // ================= epilogue: acc += (a * SCALE) @ w_b =================
    __syncthreads();
    // Write lora activations a (C-layout: col=lane&15 is r, row=quad*4+reg) into
    // As[m][r], r in [0,16); zero-pad As[m][16..32) so we can reuse the K=32 MFMA.
    if (wn == 0) {
        #pragma unroll
        for (int i = 0; i < 4; ++i) {
            int mrow = wm*64 + i*16 + quad*4;
            #pragma unroll
            for (int r = 0; r < 4; ++r)
                As[mrow + r][lrow] = (bf16)(accA[i][r] * SCALE);
        }
    } else {
        #pragma unroll
        for (int i = 0; i < 4; ++i) {
            int mrow = wm*64 + i*16 + quad*4;
            #pragma unroll
            for (int r = 0; r < 4; ++r)
                As[mrow + r][16 + lrow] = (bf16)0.f;
        }
    }
    // stage w_b: [r][n] -> Bs[n][r], zero-padded r=16..32
    {
        int n  = tid & 127;
        int r0 = (tid >> 7) * 8;
        const float* p = wbb_e + (size_t)r0 * NDIM + n0 + n;
        bf16x8 v;
        #pragma unroll
        for (int u = 0; u < 8; ++u) v[u] = (bf16)p[(size_t)u * NDIM];
        *reinterpret_cast<bf16x8*>(&Bs[n][r0]) = v;
        bf16x8 z = {};
        *reinterpret_cast<bf16x8*>(&Bs[n][16 + r0]) = z;
    }
    __syncthreads();
    #pragma unroll
    for (int i = 0; i < 4; ++i) {
        bf16x8 af2 = *reinterpret_cast<const bf16x8*>(&As[wm*64 + i*16 + lrow][quad*8]);
        #pragma unroll
        for (int j = 0; j < 4; ++j) {
            bf16x8 bf2 = *reinterpret_cast<const bf16x8*>(&Bs[wn*64 + j*16 + lrow][quad*8]);
            acc[i][j] = __builtin_amdgcn_mfma_f32_16x16x32_bf16(af2, bf2, acc[i][j], 0, 0, 0);
        }
    }

    // ---- store (mask rows beyond this expert's tile) ----
    #pragma unroll
    for (int i = 0; i < 4; ++i) {
        int mbase = wm*64 + i*16 + quad*4;
        #pragma unroll
        for (int j = 0; j < 4; ++j) {
            int col = n0 + wn*64 + j*16 + lrow;
            #pragma unroll
            for (int r = 0; r < 4; ++r) {
                int mr = mbase + r;
                if (mr < rows)
                    out[(size_t)(tstart + mr) * NDIM + col] = acc[i][j][r];
            }
        }
    }
}

extern "C" void kernel_launch(void* const* d_in, const int* in_sizes, int n_in,
                              void* d_out, int out_size, void* d_ws, size_t ws_size,
                              hipStream_t stream) {
    const float* x       = (const float*)d_in[0];
    const int*   m_sizes = (const int*)  d_in[1];
    const float* w_base  = (const float*)d_in[2];
    const float* w_a     = (const float*)d_in[3];
    const float* w_b     = (const float*)d_in[4];
    float* out = (float*)d_out;

    dim3 grid(NDIM / BN, MAXMT, 1);   // 6 n-tiles x 320 worst-case m-tiles
    lora_moe_kernel<<<grid, 256, 0, stream>>>(x, m_sizes, w_base, w_a, w_b, out);
}